// Round 3
// baseline (1554.418 us; speedup 1.0000x reference)
//
#include <hip/hip_runtime.h>
#include <hip/hip_bf16.h>
#include <cstdint>

// Problem constants (fixed by the reference).
static constexpr int N = 100000;
static constexpr int E = 3200000;
static constexpr float BN_EPS = 1e-5f;
static constexpr int NBUCK = (N + 127) >> 7;          // 782 buckets of 128 nodes

// ---------------- workspace layout ----------------
// zeroed region: coarse counts + BN sums
static constexpr size_t OFF_CCNT_D = 0;                 // NBUCK*16 int (padded: 1 ctr / 64B line)
static constexpr size_t OFF_CCNT_S = 51200;             // NBUCK*16 int
static constexpr size_t OFF_SUMS1  = 102400;            // 256 f32 (sum | sumsq)
static constexpr size_t OFF_SUMS2  = 103424;            // 256 f32
static constexpr size_t MEMSET_BYTES = 104448;
// non-zeroed
static constexpr size_t OFF_CUR_D  = 104448;            // NBUCK*16 int (cursors, init by k_scanb)
static constexpr size_t OFF_CUR_S  = 155648;            // NBUCK*16 int
static constexpr size_t OFF_DBASE  = 206848;            // NBUCK+1 int
static constexpr size_t OFF_SBASE  = 210944;            // NBUCK+1 int
static constexpr size_t OFF_AB1    = 215040;            // 256 f32 (a|c)
static constexpr size_t OFF_AB2    = 216064;            // 256 f32
static constexpr size_t OFF_NORM_S = 217088;            // N f32
static constexpr size_t OFF_NORM_D = 617472;            // N f32
static constexpr size_t OFF_RP     = 1017856;           // N+1 int
static constexpr size_t OFF_COL    = 1419264;           // E int
static constexpr size_t OFF_H      = 14219264;          // N*128 bf16
static constexpr size_t OFF_T      = 39819264;          // N*128 bf16
static constexpr size_t OFF_PAIRS  = 65419264;          // E uint (s | dloc<<20)
static constexpr size_t OFF_SRCB   = 78219264;          // E uchar (src bucket-local)

__device__ inline float ldf(const float* p, int i) { return p[i]; }
__device__ inline float ldf(const __hip_bfloat16* p, int i) { return __bfloat162float(p[i]); }
__device__ inline float bflo(unsigned v) { return __uint_as_float(v << 16); }
__device__ inline float bfhi(unsigned v) { return __uint_as_float(v & 0xffff0000u); }
__device__ inline unsigned short bfbits(float x) {
    __hip_bfloat16 h = __float2bfloat16(x);
    return *reinterpret_cast<unsigned short*>(&h);
}

// ---------------- graph preprocessing ----------------
// coarse per-bucket edge counts (hot-line atomics: cheap)
__global__ __launch_bounds__(256) void k_coarse(const int* __restrict__ src,
                                                const int* __restrict__ dst,
                                                int* __restrict__ ccnt_s,
                                                int* __restrict__ ccnt_d) {
    int e = blockIdx.x * 256 + threadIdx.x;
    if (e < E) {
        atomicAdd(&ccnt_s[(src[e] >> 7) * 16], 1);
        atomicAdd(&ccnt_d[(dst[e] >> 7) * 16], 1);
    }
}

// single-block scan of both coarse count arrays -> bases + cursors
__global__ __launch_bounds__(1024) void k_scanb(const int* __restrict__ ccnt_d,
                                                const int* __restrict__ ccnt_s,
                                                int* __restrict__ dbase,
                                                int* __restrict__ sbase,
                                                int* __restrict__ dcur,
                                                int* __restrict__ scur) {
    __shared__ int sd[1024], ss[1024];
    int tid = threadIdx.x;
    int vd = (tid < NBUCK) ? ccnt_d[tid * 16] : 0;
    int vs = (tid < NBUCK) ? ccnt_s[tid * 16] : 0;
    sd[tid] = vd; ss[tid] = vs;
    __syncthreads();
    for (int off = 1; off < 1024; off <<= 1) {
        int td = (tid >= off) ? sd[tid - off] : 0;
        int ts = (tid >= off) ? ss[tid - off] : 0;
        __syncthreads();
        sd[tid] += td; ss[tid] += ts;
        __syncthreads();
    }
    if (tid < NBUCK) {
        int ed = sd[tid] - vd, es = ss[tid] - vs;
        dbase[tid] = ed; sbase[tid] = es;
        dcur[tid * 16] = ed; scur[tid * 16] = es;
    }
    if (tid == 0) { dbase[NBUCK] = E; sbase[NBUCK] = E; }
}

// scatter packed (dst-local | src) into dst-bucket ranges
__global__ __launch_bounds__(256) void k_pairs(const int* __restrict__ src,
                                               const int* __restrict__ dst,
                                               int* __restrict__ dcur,
                                               unsigned* __restrict__ pairs) {
    int e = blockIdx.x * 256 + threadIdx.x;
    if (e < E) {
        int s = src[e], d = dst[e];
        int pos = atomicAdd(&dcur[(d >> 7) * 16], 1);
        pairs[pos] = (unsigned)s | ((unsigned)(d & 127) << 20);
    }
}

// scatter src bucket-local bytes into src-bucket ranges
__global__ __launch_bounds__(256) void k_ssc(const int* __restrict__ src,
                                             int* __restrict__ scur,
                                             unsigned char* __restrict__ srcb) {
    int e = blockIdx.x * 256 + threadIdx.x;
    if (e < E) {
        int s = src[e];
        int pos = atomicAdd(&scur[(s >> 7) * 16], 1);
        srcb[pos] = (unsigned char)(s & 127);
    }
}

// per src-bucket: LDS histogram -> norm_s
__global__ __launch_bounds__(256) void k_degout(const unsigned char* __restrict__ srcb,
                                                const int* __restrict__ sbase,
                                                float* __restrict__ norm_s) {
    __shared__ int cnt[128];
    int b = blockIdx.x, tid = threadIdx.x, node0 = b << 7;
    if (tid < 128) cnt[tid] = 0;
    __syncthreads();
    int beg = sbase[b], end = sbase[b + 1];
    for (int e = beg + tid; e < end; e += 256) atomicAdd(&cnt[srcb[e]], 1);
    __syncthreads();
    int nmax = min(128, N - node0);
    if (tid < nmax) norm_s[node0 + tid] = rsqrtf(fmaxf((float)cnt[tid], 1.0f));
}

// per dst-bucket: LDS histogram -> norm_d, LDS scan -> rp, LDS cursors -> col
__global__ __launch_bounds__(256) void k_build(const unsigned* __restrict__ pairs,
                                               const int* __restrict__ dbase,
                                               int* __restrict__ rp,
                                               float* __restrict__ norm_d,
                                               int* __restrict__ col) {
    __shared__ int cnt[128], scn[128], lcur[128];
    int b = blockIdx.x, tid = threadIdx.x, node0 = b << 7;
    if (tid < 128) cnt[tid] = 0;
    __syncthreads();
    int beg = dbase[b], end = dbase[b + 1];
    for (int e = beg + tid; e < end; e += 256) atomicAdd(&cnt[pairs[e] >> 20], 1);
    __syncthreads();
    if (tid < 128) scn[tid] = cnt[tid];
    __syncthreads();
    for (int off = 1; off < 128; off <<= 1) {
        int t = (tid < 128 && tid >= off) ? scn[tid - off] : 0;
        __syncthreads();
        if (tid < 128) scn[tid] += t;
        __syncthreads();
    }
    int nmax = min(128, N - node0);
    if (tid < nmax) {
        int excl = beg + scn[tid] - cnt[tid];
        rp[node0 + tid] = excl;
        lcur[tid] = excl;
        norm_d[node0 + tid] = rsqrtf(fmaxf((float)cnt[tid], 1.0f));
    }
    if (b == 0 && tid == 0) rp[N] = E;
    __syncthreads();
    for (int e = beg + tid; e < end; e += 256) {
        unsigned p = pairs[e];
        int pos = atomicAdd(&lcur[p >> 20], 1);
        col[pos] = (int)(p & 0xFFFFFu);
    }
}

// ---------------- GEMM: t = ((in * a + c) * norm_s) @ W, out bf16 ----------------
template <typename TIn, int FOUT, bool AFFINE>
__global__ __launch_bounds__(256) void k_gemm(const TIn* __restrict__ in,
                                              const float* __restrict__ W,
                                              const float* __restrict__ rowscale,
                                              const float* __restrict__ ab, // a[0..127], c[128..255]
                                              __hip_bfloat16* __restrict__ out) {
    __shared__ float Ws[64 * FOUT];
    __shared__ float Xs[32][128];
    const int tid = threadIdx.x;
    const int r0 = blockIdx.x * 32;

    for (int i = tid; i < 32 * 128; i += 256) {
        int rr = i >> 7, k = i & 127;
        int row = r0 + rr;
        float v = 0.0f;
        if (row < N) {
            v = ldf(in, row * 128 + k);
            if (AFFINE) v = v * ab[k] + ab[128 + k];
            v *= rowscale[row];
        }
        Xs[rr][k] = v;
    }

    const int wave = tid >> 6, lane = tid & 63;
    constexpr int NC = FOUT / 64;
    float acc[8][NC];
#pragma unroll
    for (int rr = 0; rr < 8; ++rr)
#pragma unroll
        for (int cc = 0; cc < NC; ++cc) acc[rr][cc] = 0.0f;

    for (int kb = 0; kb < 128; kb += 64) {
        __syncthreads();
        for (int i = tid; i < 64 * FOUT; i += 256)
            Ws[i] = W[(size_t)(kb + i / FOUT) * FOUT + (i % FOUT)];
        __syncthreads();
#pragma unroll 4
        for (int k = 0; k < 64; ++k) {
            float w0 = Ws[k * FOUT + lane];
            float w1 = (NC == 2) ? Ws[k * FOUT + 64 + lane] : 0.0f;
#pragma unroll
            for (int rr = 0; rr < 8; ++rr) {
                float xv = Xs[wave * 8 + rr][kb + k];
                acc[rr][0] += xv * w0;
                if (NC == 2) acc[rr][1] += xv * w1;
            }
        }
    }

#pragma unroll
    for (int rr = 0; rr < 8; ++rr) {
        int row = r0 + wave * 8 + rr;
        if (row < N) {
            out[(size_t)row * FOUT + lane] = __float2bfloat16(acc[rr][0]);
            if (NC == 2) out[(size_t)row * FOUT + lane + 64] = __float2bfloat16(acc[rr][1]);
        }
    }
}

// ------- fused aggregation (128 feats) + norm_d + bias + relu + bf16 H + BN stats -------
__global__ __launch_bounds__(256) void k_agg128f(const unsigned* __restrict__ T2, // N x 64 uints
                                                 const int* __restrict__ rp,
                                                 const int* __restrict__ col,
                                                 const float* __restrict__ norm_d,
                                                 const float* __restrict__ bias,
                                                 unsigned* __restrict__ Hu,      // N x 64 uints
                                                 float* __restrict__ sums) {
    int wave = threadIdx.x >> 6, lane = threadIdx.x & 63;
    int f0 = 2 * lane, f1 = 2 * lane + 1;
    float bb0 = bias[f0], bb1 = bias[f1];
    float s0 = 0.f, q0 = 0.f, s1 = 0.f, q1 = 0.f;
    for (int n = blockIdx.x * 4 + wave; n < N; n += 4096) {
        int beg = rp[n], end = rp[n + 1];
        float a0 = 0.0f, a1 = 0.0f;
        int e = beg;
        for (; e + 4 <= end; e += 4) {
            int c0 = col[e], c1 = col[e + 1], c2 = col[e + 2], c3 = col[e + 3];
            unsigned v0 = T2[c0 * 64 + lane];
            unsigned v1 = T2[c1 * 64 + lane];
            unsigned v2 = T2[c2 * 64 + lane];
            unsigned v3 = T2[c3 * 64 + lane];
            a0 += bflo(v0) + bflo(v1) + bflo(v2) + bflo(v3);
            a1 += bfhi(v0) + bfhi(v1) + bfhi(v2) + bfhi(v3);
        }
        for (; e < end; ++e) {
            unsigned v = T2[col[e] * 64 + lane];
            a0 += bflo(v); a1 += bfhi(v);
        }
        float nd = norm_d[n];
        float r0 = fmaxf(a0 * nd + bb0, 0.0f);
        float r1 = fmaxf(a1 * nd + bb1, 0.0f);
        Hu[n * 64 + lane] = ((unsigned)bfbits(r1) << 16) | bfbits(r0);
        s0 += r0; q0 += r0 * r0; s1 += r1; q1 += r1 * r1;
    }
    __shared__ float red[4][64][4];
    red[wave][lane][0] = s0; red[wave][lane][1] = q0;
    red[wave][lane][2] = s1; red[wave][lane][3] = q1;
    __syncthreads();
    if (wave == 0) {
        float t0 = 0.f, t1 = 0.f, t2 = 0.f, t3 = 0.f;
        for (int w = 0; w < 4; ++w) {
            t0 += red[w][lane][0]; t1 += red[w][lane][1];
            t2 += red[w][lane][2]; t3 += red[w][lane][3];
        }
        atomicAdd(&sums[f0], t0);
        atomicAdd(&sums[128 + f0], t1);
        atomicAdd(&sums[f1], t2);
        atomicAdd(&sums[128 + f1], t3);
    }
}

__global__ __launch_bounds__(128) void k_bnfin(const float* __restrict__ sums,
                                               const float* __restrict__ gamma,
                                               const float* __restrict__ beta,
                                               float* __restrict__ ab) {
    int f = threadIdx.x;
    float mu = sums[f] * (1.0f / N);
    float var = sums[128 + f] * (1.0f / N) - mu * mu;
    float a = gamma[f] * rsqrtf(var + BN_EPS);
    ab[f] = a;
    ab[128 + f] = beta[f] - mu * a;
}

// ------- fused aggregation (64 feats) + norm_d + bias + log_softmax -------
__global__ __launch_bounds__(256) void k_agg64f(const __hip_bfloat16* __restrict__ T,
                                                const int* __restrict__ rp,
                                                const int* __restrict__ col,
                                                const float* __restrict__ norm_d,
                                                const float* __restrict__ b3,
                                                float* __restrict__ out) {
    int wave = threadIdx.x >> 6, lane = threadIdx.x & 63;
    int n = blockIdx.x * 4 + wave;
    if (n >= N) return;
    int beg = rp[n], end = rp[n + 1];
    float a0 = 0.0f;
    int e = beg;
    for (; e + 4 <= end; e += 4) {
        int c0 = col[e], c1 = col[e + 1], c2 = col[e + 2], c3 = col[e + 3];
        float v0 = __bfloat162float(T[c0 * 64 + lane]);
        float v1 = __bfloat162float(T[c1 * 64 + lane]);
        float v2 = __bfloat162float(T[c2 * 64 + lane]);
        float v3 = __bfloat162float(T[c3 * 64 + lane]);
        a0 += v0 + v1 + v2 + v3;
    }
    for (; e < end; ++e) a0 += __bfloat162float(T[col[e] * 64 + lane]);
    float z = a0 * norm_d[n] + b3[lane];
    float m = z;
    for (int off = 32; off; off >>= 1) m = fmaxf(m, __shfl_xor(m, off));
    float ex = __expf(z - m);
    float ssum = ex;
    for (int off = 32; off; off >>= 1) ssum += __shfl_xor(ssum, off);
    out[n * 64 + lane] = z - m - __logf(ssum);
}

extern "C" void kernel_launch(void* const* d_in, const int* in_sizes, int n_in,
                              void* d_out, int out_size, void* d_ws, size_t ws_size,
                              hipStream_t stream) {
    const float* x  = (const float*)d_in[0];
    const int* src  = (const int*)d_in[1];
    const int* dst  = (const int*)d_in[2];
    const float* W1 = (const float*)d_in[3];
    const float* b1 = (const float*)d_in[4];
    const float* W2 = (const float*)d_in[5];
    const float* b2 = (const float*)d_in[6];
    const float* W3 = (const float*)d_in[7];
    const float* b3 = (const float*)d_in[8];
    const float* g1 = (const float*)d_in[9];
    const float* be1= (const float*)d_in[10];
    const float* g2 = (const float*)d_in[11];
    const float* be2= (const float*)d_in[12];
    float* out = (float*)d_out;

    char* ws = (char*)d_ws;
    int* ccnt_d = (int*)(ws + OFF_CCNT_D);
    int* ccnt_s = (int*)(ws + OFF_CCNT_S);
    float* sums1 = (float*)(ws + OFF_SUMS1);
    float* sums2 = (float*)(ws + OFF_SUMS2);
    int* dcur = (int*)(ws + OFF_CUR_D);
    int* scur = (int*)(ws + OFF_CUR_S);
    int* dbase = (int*)(ws + OFF_DBASE);
    int* sbase = (int*)(ws + OFF_SBASE);
    float* ab1 = (float*)(ws + OFF_AB1);
    float* ab2 = (float*)(ws + OFF_AB2);
    float* norm_s = (float*)(ws + OFF_NORM_S);
    float* norm_d = (float*)(ws + OFF_NORM_D);
    int* rp = (int*)(ws + OFF_RP);
    int* col = (int*)(ws + OFF_COL);
    __hip_bfloat16* H = (__hip_bfloat16*)(ws + OFF_H);
    __hip_bfloat16* T = (__hip_bfloat16*)(ws + OFF_T);
    unsigned* pairs = (unsigned*)(ws + OFF_PAIRS);
    unsigned char* srcb = (unsigned char*)(ws + OFF_SRCB);

    hipMemsetAsync(ws, 0, MEMSET_BYTES, stream);

    const int egrid = (E + 255) / 256;
    k_coarse<<<egrid, 256, 0, stream>>>(src, dst, ccnt_s, ccnt_d);
    k_scanb<<<1, 1024, 0, stream>>>(ccnt_d, ccnt_s, dbase, sbase, dcur, scur);
    k_pairs<<<egrid, 256, 0, stream>>>(src, dst, dcur, pairs);
    k_ssc<<<egrid, 256, 0, stream>>>(src, scur, srcb);
    k_degout<<<NBUCK, 256, 0, stream>>>(srcb, sbase, norm_s);
    k_build<<<NBUCK, 256, 0, stream>>>(pairs, dbase, rp, norm_d, col);

    const int gemm_grid = (N + 31) / 32;
    const int node_grid = (N + 3) / 4;

    // Layer 1
    k_gemm<float, 128, false><<<gemm_grid, 256, 0, stream>>>(x, W1, norm_s, nullptr, T);
    k_agg128f<<<1024, 256, 0, stream>>>((const unsigned*)T, rp, col, norm_d, b1, (unsigned*)H, sums1);
    k_bnfin<<<1, 128, 0, stream>>>(sums1, g1, be1, ab1);

    // Layer 2
    k_gemm<__hip_bfloat16, 128, true><<<gemm_grid, 256, 0, stream>>>(H, W2, norm_s, ab1, T);
    k_agg128f<<<1024, 256, 0, stream>>>((const unsigned*)T, rp, col, norm_d, b2, (unsigned*)H, sums2);
    k_bnfin<<<1, 128, 0, stream>>>(sums2, g2, be2, ab2);

    // Layer 3 (64 outputs) + log_softmax
    k_gemm<__hip_bfloat16, 64, true><<<gemm_grid, 256, 0, stream>>>(H, W3, norm_s, ab2, T);
    k_agg64f<<<node_grid, 256, 0, stream>>>(T, rp, col, norm_d, b3, out);
}

// Round 4
// 1012.637 us; speedup vs baseline: 1.5350x; 1.5350x over previous
//
#include <hip/hip_runtime.h>
#include <hip/hip_bf16.h>
#include <cstdint>

// Problem constants (fixed by the reference).
static constexpr int N = 100000;
static constexpr int E = 3200000;
static constexpr float BN_EPS = 1e-5f;
static constexpr int NBUCK = (N + 127) >> 7;   // 782 buckets of 128 nodes
static constexpr int NBLK = 256;               // edge-counting blocks
static constexpr int CHUNK = E / NBLK;         // 12500 edges per block (exact)
static constexpr int AGG_BLOCKS = 1024;        // agg128 grid
static constexpr int NCHUNK = (N + AGG_BLOCKS * 4 - 1) / (AGG_BLOCKS * 4); // 25 nodes/wave

// ---------------- workspace layout (no zero-init required anywhere) ----------------
static constexpr size_t OFF_TOT_D = 0;              // NBUCK int
static constexpr size_t OFF_TOT_S = 3328;           // NBUCK int
static constexpr size_t OFF_DBASE = 6656;           // NBUCK+1 int
static constexpr size_t OFF_SBASE = 9984;           // NBUCK+1 int
static constexpr size_t OFF_AB1   = 13312;          // 256 f32 (a|c)
static constexpr size_t OFF_AB2   = 14336;          // 256 f32
static constexpr size_t OFF_BNP   = 15360;          // AGG_BLOCKS*256 f32 = 1 MB
static constexpr size_t OFF_NORM_S= 1063936;        // N f32
static constexpr size_t OFF_NORM_D= 1463936;        // N f32
static constexpr size_t OFF_RP    = 1863936;        // N+1 int
static constexpr size_t OFF_CNT_D = 2264064;        // NBLK*NBUCK int
static constexpr size_t OFF_CNT_S = 3064832;        // NBLK*NBUCK int
static constexpr size_t OFF_OFFD  = 3865600;        // NBLK*NBUCK int
static constexpr size_t OFF_OFFS  = 4666368;        // NBLK*NBUCK int
static constexpr size_t OFF_COL   = 5467136;        // E int
static constexpr size_t OFF_SRCB  = 18267136;       // E uchar
static constexpr size_t OFF_PAIRS = 21467136;       // E uint (s | dloc<<20)
static constexpr size_t OFF_H     = 34267136;       // N*128 bf16
static constexpr size_t OFF_T     = 59867136;       // N*128 bf16

__device__ inline float ldf(const float* p, int i) { return p[i]; }
__device__ inline float ldf(const __hip_bfloat16* p, int i) { return __bfloat162float(p[i]); }
__device__ inline float bflo(unsigned v) { return __uint_as_float(v << 16); }
__device__ inline float bfhi(unsigned v) { return __uint_as_float(v & 0xffff0000u); }
__device__ inline unsigned short bfbits(float x) {
    __hip_bfloat16 h = __float2bfloat16(x);
    return *reinterpret_cast<unsigned short*>(&h);
}

// ---- pass 1: per-block privatized bucket histograms (LDS atomics only) ----
__global__ __launch_bounds__(256) void k_count(const int* __restrict__ src,
                                               const int* __restrict__ dst,
                                               int* __restrict__ cnt_s,
                                               int* __restrict__ cnt_d) {
    __shared__ int hs[NBUCK], hd[NBUCK];
    int tid = threadIdx.x, blk = blockIdx.x;
    for (int b = tid; b < NBUCK; b += 256) { hs[b] = 0; hd[b] = 0; }
    __syncthreads();
    int e0 = blk * CHUNK, e1 = min(E, e0 + CHUNK);
    for (int e = e0 + tid; e < e1; e += 256) {
        atomicAdd(&hs[src[e] >> 7], 1);
        atomicAdd(&hd[dst[e] >> 7], 1);
    }
    __syncthreads();
    for (int b = tid; b < NBUCK; b += 256) {
        cnt_s[blk * NBUCK + b] = hs[b];
        cnt_d[blk * NBUCK + b] = hd[b];
    }
}

// ---- pass 2a: per-bucket scan over the 256 counting blocks ----
__global__ __launch_bounds__(256) void k_scanA(const int* __restrict__ cnt,
                                               int* __restrict__ off,
                                               int* __restrict__ tot) {
    __shared__ int sd[256];
    int b = blockIdx.x, tid = threadIdx.x;
    int v = cnt[tid * NBUCK + b];
    sd[tid] = v;
    __syncthreads();
    for (int o = 1; o < 256; o <<= 1) {
        int t = (tid >= o) ? sd[tid - o] : 0;
        __syncthreads();
        sd[tid] += t;
        __syncthreads();
    }
    off[tid * NBUCK + b] = sd[tid] - v;
    if (tid == 255) tot[b] = sd[255];
}

// ---- pass 2b: scan bucket totals -> bases ----
__global__ __launch_bounds__(1024) void k_scanB(const int* __restrict__ tot_d,
                                                const int* __restrict__ tot_s,
                                                int* __restrict__ dbase,
                                                int* __restrict__ sbase) {
    __shared__ int sd[1024], ss[1024];
    int tid = threadIdx.x;
    int vd = (tid < NBUCK) ? tot_d[tid] : 0;
    int vs = (tid < NBUCK) ? tot_s[tid] : 0;
    sd[tid] = vd; ss[tid] = vs;
    __syncthreads();
    for (int o = 1; o < 1024; o <<= 1) {
        int td = (tid >= o) ? sd[tid - o] : 0;
        int ts = (tid >= o) ? ss[tid - o] : 0;
        __syncthreads();
        sd[tid] += td; ss[tid] += ts;
        __syncthreads();
    }
    if (tid < NBUCK) { dbase[tid] = sd[tid] - vd; sbase[tid] = ss[tid] - vs; }
    if (tid == 0) { dbase[NBUCK] = E; sbase[NBUCK] = E; }
}

// ---- pass 3: deterministic-offset scatter (LDS cursors, zero global atomics) ----
__global__ __launch_bounds__(256) void k_scatter(const int* __restrict__ src,
                                                 const int* __restrict__ dst,
                                                 const int* __restrict__ dbase,
                                                 const int* __restrict__ sbase,
                                                 const int* __restrict__ offd,
                                                 const int* __restrict__ offs,
                                                 unsigned* __restrict__ pairs,
                                                 unsigned char* __restrict__ srcb) {
    __shared__ int cd[NBUCK], cs[NBUCK];
    int tid = threadIdx.x, blk = blockIdx.x;
    for (int b = tid; b < NBUCK; b += 256) {
        cd[b] = dbase[b] + offd[blk * NBUCK + b];
        cs[b] = sbase[b] + offs[blk * NBUCK + b];
    }
    __syncthreads();
    int e0 = blk * CHUNK, e1 = min(E, e0 + CHUNK);
    for (int e = e0 + tid; e < e1; e += 256) {
        int s = src[e], d = dst[e];
        int pd = atomicAdd(&cd[d >> 7], 1);
        pairs[pd] = (unsigned)s | ((unsigned)(d & 127) << 20);
        int ps = atomicAdd(&cs[s >> 7], 1);
        srcb[ps] = (unsigned char)(s & 127);
    }
}

// ---- pass 4: per-bucket degrees/norms/rp/col (LDS only) ----
__global__ __launch_bounds__(256) void k_build(const unsigned* __restrict__ pairs,
                                               const unsigned char* __restrict__ srcb,
                                               const int* __restrict__ dbase,
                                               const int* __restrict__ sbase,
                                               int* __restrict__ rp,
                                               float* __restrict__ norm_d,
                                               float* __restrict__ norm_s,
                                               int* __restrict__ col) {
    __shared__ int cnt[128], scn[128], lcur[128];
    int b = blockIdx.x, tid = threadIdx.x, node0 = b << 7;
    int nmax = min(128, N - node0);
    // src side: out-degree -> norm_s
    if (tid < 128) cnt[tid] = 0;
    __syncthreads();
    int sb = sbase[b], se = sbase[b + 1];
    for (int e = sb + tid; e < se; e += 256) atomicAdd(&cnt[srcb[e]], 1);
    __syncthreads();
    if (tid < nmax) norm_s[node0 + tid] = rsqrtf(fmaxf((float)cnt[tid], 1.0f));
    __syncthreads();
    // dst side: in-degree -> norm_d, rp, col
    if (tid < 128) cnt[tid] = 0;
    __syncthreads();
    int beg = dbase[b], end = dbase[b + 1];
    for (int e = beg + tid; e < end; e += 256) atomicAdd(&cnt[pairs[e] >> 20], 1);
    __syncthreads();
    if (tid < 128) scn[tid] = cnt[tid];
    __syncthreads();
    for (int o = 1; o < 128; o <<= 1) {
        int t = (tid < 128 && tid >= o) ? scn[tid - o] : 0;
        __syncthreads();
        if (tid < 128) scn[tid] += t;
        __syncthreads();
    }
    if (tid < nmax) {
        int excl = beg + scn[tid] - cnt[tid];
        rp[node0 + tid] = excl;
        lcur[tid] = excl;
        norm_d[node0 + tid] = rsqrtf(fmaxf((float)cnt[tid], 1.0f));
    }
    if (b == 0 && tid == 0) rp[N] = E;
    __syncthreads();
    for (int e = beg + tid; e < end; e += 256) {
        unsigned p = pairs[e];
        int pos = atomicAdd(&lcur[p >> 20], 1);
        col[pos] = (int)(p & 0xFFFFFu);
    }
}

// ---------------- GEMM: t = ((in * a + c) * norm_s) @ W, out bf16 ----------------
template <typename TIn, int FOUT, bool AFFINE>
__global__ __launch_bounds__(256) void k_gemm(const TIn* __restrict__ in,
                                              const float* __restrict__ W,
                                              const float* __restrict__ rowscale,
                                              const float* __restrict__ ab, // a[0..127], c[128..255]
                                              __hip_bfloat16* __restrict__ out) {
    __shared__ float Ws[64 * FOUT];
    __shared__ float Xs[32][128];
    const int tid = threadIdx.x;
    const int r0 = blockIdx.x * 32;

    for (int i = tid; i < 32 * 128; i += 256) {
        int rr = i >> 7, k = i & 127;
        int row = r0 + rr;
        float v = 0.0f;
        if (row < N) {
            v = ldf(in, row * 128 + k);
            if (AFFINE) v = v * ab[k] + ab[128 + k];
            v *= rowscale[row];
        }
        Xs[rr][k] = v;
    }

    const int wave = tid >> 6, lane = tid & 63;
    constexpr int NC = FOUT / 64;
    float acc[8][NC];
#pragma unroll
    for (int rr = 0; rr < 8; ++rr)
#pragma unroll
        for (int cc = 0; cc < NC; ++cc) acc[rr][cc] = 0.0f;

    for (int kb = 0; kb < 128; kb += 64) {
        __syncthreads();
        for (int i = tid; i < 64 * FOUT; i += 256)
            Ws[i] = W[(size_t)(kb + i / FOUT) * FOUT + (i % FOUT)];
        __syncthreads();
#pragma unroll 4
        for (int k = 0; k < 64; ++k) {
            float w0 = Ws[k * FOUT + lane];
            float w1 = (NC == 2) ? Ws[k * FOUT + 64 + lane] : 0.0f;
#pragma unroll
            for (int rr = 0; rr < 8; ++rr) {
                float xv = Xs[wave * 8 + rr][kb + k];
                acc[rr][0] += xv * w0;
                if (NC == 2) acc[rr][1] += xv * w1;
            }
        }
    }

#pragma unroll
    for (int rr = 0; rr < 8; ++rr) {
        int row = r0 + wave * 8 + rr;
        if (row < N) {
            out[(size_t)row * FOUT + lane] = __float2bfloat16(acc[rr][0]);
            if (NC == 2) out[(size_t)row * FOUT + lane + 64] = __float2bfloat16(acc[rr][1]);
        }
    }
}

// ------- fused aggregation (128 feats) + norm_d + bias + relu + bf16 H + BN partials -------
__global__ __launch_bounds__(256) void k_agg128f(const unsigned* __restrict__ T2, // N x 64 uints
                                                 const int* __restrict__ rp,
                                                 const int* __restrict__ col,
                                                 const float* __restrict__ norm_d,
                                                 const float* __restrict__ bias,
                                                 unsigned* __restrict__ Hu,      // N x 64 uints
                                                 float* __restrict__ part) {
    int tid = threadIdx.x, wave = tid >> 6, lane = tid & 63;
    int w = blockIdx.x * 4 + wave;
    int n0 = w * NCHUNK, n1 = min(N, n0 + NCHUNK);
    float bb0 = bias[2 * lane], bb1 = bias[2 * lane + 1];
    float s0 = 0.f, q0 = 0.f, s1 = 0.f, q1 = 0.f;
    for (int n = n0; n < n1; ++n) {
        int beg = rp[n], end = rp[n + 1];
        float a0 = 0.0f, a1 = 0.0f;
        int e = beg;
        for (; e + 4 <= end; e += 4) {
            int c0 = col[e], c1 = col[e + 1], c2 = col[e + 2], c3 = col[e + 3];
            unsigned v0 = T2[c0 * 64 + lane];
            unsigned v1 = T2[c1 * 64 + lane];
            unsigned v2 = T2[c2 * 64 + lane];
            unsigned v3 = T2[c3 * 64 + lane];
            a0 += bflo(v0) + bflo(v1) + bflo(v2) + bflo(v3);
            a1 += bfhi(v0) + bfhi(v1) + bfhi(v2) + bfhi(v3);
        }
        for (; e < end; ++e) {
            unsigned v = T2[col[e] * 64 + lane];
            a0 += bflo(v); a1 += bfhi(v);
        }
        float nd = norm_d[n];
        float r0 = fmaxf(a0 * nd + bb0, 0.0f);
        float r1 = fmaxf(a1 * nd + bb1, 0.0f);
        Hu[n * 64 + lane] = ((unsigned)bfbits(r1) << 16) | bfbits(r0);
        s0 += r0; q0 += r0 * r0; s1 += r1; q1 += r1 * r1;
    }
    __shared__ float red[4][256];
    red[wave][lane] = s0;
    red[wave][64 + lane] = q0;
    red[wave][128 + lane] = s1;
    red[wave][192 + lane] = q1;
    __syncthreads();
    float t = red[0][tid] + red[1][tid] + red[2][tid] + red[3][tid];
    part[blockIdx.x * 256 + tid] = t;
}

// reduce BN partials -> folded affine (a|c)
__global__ __launch_bounds__(256) void k_bnfin(const float* __restrict__ part,
                                               const float* __restrict__ gamma,
                                               const float* __restrict__ beta,
                                               float* __restrict__ ab) {
    __shared__ float slot[256];
    int tid = threadIdx.x;
    float a = 0.f;
    for (int blk = 0; blk < AGG_BLOCKS; blk += 4) {
        a += part[(blk + 0) * 256 + tid] + part[(blk + 1) * 256 + tid]
           + part[(blk + 2) * 256 + tid] + part[(blk + 3) * 256 + tid];
    }
    slot[tid] = a;
    __syncthreads();
    if (tid < 128) {
        int l = tid >> 1;
        float sum, sq;
        if ((tid & 1) == 0) { sum = slot[l];       sq = slot[64 + l]; }
        else                { sum = slot[128 + l]; sq = slot[192 + l]; }
        float mu = sum * (1.0f / N);
        float var = sq * (1.0f / N) - mu * mu;
        float aa = gamma[tid] * rsqrtf(var + BN_EPS);
        ab[tid] = aa;
        ab[128 + tid] = beta[tid] - mu * aa;
    }
}

// ------- fused aggregation (64 feats) + norm_d + bias + log_softmax -------
__global__ __launch_bounds__(256) void k_agg64f(const __hip_bfloat16* __restrict__ T,
                                                const int* __restrict__ rp,
                                                const int* __restrict__ col,
                                                const float* __restrict__ norm_d,
                                                const float* __restrict__ b3,
                                                float* __restrict__ out) {
    int wave = threadIdx.x >> 6, lane = threadIdx.x & 63;
    int n = blockIdx.x * 4 + wave;
    if (n >= N) return;
    int beg = rp[n], end = rp[n + 1];
    float a0 = 0.0f;
    int e = beg;
    for (; e + 4 <= end; e += 4) {
        int c0 = col[e], c1 = col[e + 1], c2 = col[e + 2], c3 = col[e + 3];
        float v0 = __bfloat162float(T[c0 * 64 + lane]);
        float v1 = __bfloat162float(T[c1 * 64 + lane]);
        float v2 = __bfloat162float(T[c2 * 64 + lane]);
        float v3 = __bfloat162float(T[c3 * 64 + lane]);
        a0 += v0 + v1 + v2 + v3;
    }
    for (; e < end; ++e) a0 += __bfloat162float(T[col[e] * 64 + lane]);
    float z = a0 * norm_d[n] + b3[lane];
    float m = z;
    for (int off = 32; off; off >>= 1) m = fmaxf(m, __shfl_xor(m, off));
    float ex = __expf(z - m);
    float ssum = ex;
    for (int off = 32; off; off >>= 1) ssum += __shfl_xor(ssum, off);
    out[n * 64 + lane] = z - m - __logf(ssum);
}

extern "C" void kernel_launch(void* const* d_in, const int* in_sizes, int n_in,
                              void* d_out, int out_size, void* d_ws, size_t ws_size,
                              hipStream_t stream) {
    const float* x  = (const float*)d_in[0];
    const int* src  = (const int*)d_in[1];
    const int* dst  = (const int*)d_in[2];
    const float* W1 = (const float*)d_in[3];
    const float* b1 = (const float*)d_in[4];
    const float* W2 = (const float*)d_in[5];
    const float* b2 = (const float*)d_in[6];
    const float* W3 = (const float*)d_in[7];
    const float* b3 = (const float*)d_in[8];
    const float* g1 = (const float*)d_in[9];
    const float* be1= (const float*)d_in[10];
    const float* g2 = (const float*)d_in[11];
    const float* be2= (const float*)d_in[12];
    float* out = (float*)d_out;

    char* ws = (char*)d_ws;
    int* tot_d = (int*)(ws + OFF_TOT_D);
    int* tot_s = (int*)(ws + OFF_TOT_S);
    int* dbase = (int*)(ws + OFF_DBASE);
    int* sbase = (int*)(ws + OFF_SBASE);
    float* ab1 = (float*)(ws + OFF_AB1);
    float* ab2 = (float*)(ws + OFF_AB2);
    float* bnp = (float*)(ws + OFF_BNP);
    float* norm_s = (float*)(ws + OFF_NORM_S);
    float* norm_d = (float*)(ws + OFF_NORM_D);
    int* rp = (int*)(ws + OFF_RP);
    int* cnt_d = (int*)(ws + OFF_CNT_D);
    int* cnt_s = (int*)(ws + OFF_CNT_S);
    int* offd = (int*)(ws + OFF_OFFD);
    int* offs = (int*)(ws + OFF_OFFS);
    int* col = (int*)(ws + OFF_COL);
    unsigned char* srcb = (unsigned char*)(ws + OFF_SRCB);
    unsigned* pairs = (unsigned*)(ws + OFF_PAIRS);
    __hip_bfloat16* H = (__hip_bfloat16*)(ws + OFF_H);
    __hip_bfloat16* T = (__hip_bfloat16*)(ws + OFF_T);

    // CSR build — zero global atomics
    k_count<<<NBLK, 256, 0, stream>>>(src, dst, cnt_s, cnt_d);
    k_scanA<<<NBUCK, 256, 0, stream>>>(cnt_d, offd, tot_d);
    k_scanA<<<NBUCK, 256, 0, stream>>>(cnt_s, offs, tot_s);
    k_scanB<<<1, 1024, 0, stream>>>(tot_d, tot_s, dbase, sbase);
    k_scatter<<<NBLK, 256, 0, stream>>>(src, dst, dbase, sbase, offd, offs, pairs, srcb);
    k_build<<<NBUCK, 256, 0, stream>>>(pairs, srcb, dbase, sbase, rp, norm_d, norm_s, col);

    const int gemm_grid = (N + 31) / 32;
    const int node_grid = (N + 3) / 4;

    // Layer 1
    k_gemm<float, 128, false><<<gemm_grid, 256, 0, stream>>>(x, W1, norm_s, nullptr, T);
    k_agg128f<<<AGG_BLOCKS, 256, 0, stream>>>((const unsigned*)T, rp, col, norm_d, b1, (unsigned*)H, bnp);
    k_bnfin<<<1, 256, 0, stream>>>(bnp, g1, be1, ab1);

    // Layer 2
    k_gemm<__hip_bfloat16, 128, true><<<gemm_grid, 256, 0, stream>>>(H, W2, norm_s, ab1, T);
    k_agg128f<<<AGG_BLOCKS, 256, 0, stream>>>((const unsigned*)T, rp, col, norm_d, b2, (unsigned*)H, bnp);
    k_bnfin<<<1, 256, 0, stream>>>(bnp, g2, be2, ab2);

    // Layer 3 (64 outputs) + log_softmax
    k_gemm<__hip_bfloat16, 64, true><<<gemm_grid, 256, 0, stream>>>(H, W3, norm_s, ab2, T);
    k_agg64f<<<node_grid, 256, 0, stream>>>(T, rp, col, norm_d, b3, out);
}

// Round 5
// 901.493 us; speedup vs baseline: 1.7243x; 1.1233x over previous
//
#include <hip/hip_runtime.h>
#include <hip/hip_bf16.h>
#include <cstdint>

// Problem constants (fixed by the reference).
static constexpr int N = 100000;
static constexpr int E = 3200000;
static constexpr float BN_EPS = 1e-5f;
static constexpr int NBUCK = (N + 127) >> 7;   // 782 buckets of 128 nodes
static constexpr int NBLK = 256;               // edge-counting blocks
static constexpr int CHUNK = E / NBLK;         // 12500 edges per block (exact)
static constexpr int AGG_BLOCKS = 2048;        // agg128 grid: 8192 waves = 100% occupancy cap
static constexpr int NCHUNK = (N + AGG_BLOCKS * 4 - 1) / (AGG_BLOCKS * 4); // 13 nodes/wave

// ---------------- workspace layout (no zero-init required anywhere) ----------------
static constexpr size_t OFF_TOT_D = 0;              // NBUCK int
static constexpr size_t OFF_TOT_S = 3328;           // NBUCK int
static constexpr size_t OFF_DBASE = 6656;           // NBUCK+1 int
static constexpr size_t OFF_SBASE = 9984;           // NBUCK+1 int
static constexpr size_t OFF_AB1   = 13312;          // 256 f32 (a|c)
static constexpr size_t OFF_AB2   = 14336;          // 256 f32
static constexpr size_t OFF_BNP   = 15360;          // AGG_BLOCKS*256 f32 = 2 MB
static constexpr size_t OFF_NORM_S= 2112512;        // N f32
static constexpr size_t OFF_NORM_D= 2512512;        // N f32
static constexpr size_t OFF_RP    = 2912512;        // N+1 int
static constexpr size_t OFF_CNT_D = 3312640;        // NBLK*NBUCK int
static constexpr size_t OFF_CNT_S = 4113408;        // NBLK*NBUCK int
static constexpr size_t OFF_OFFD  = 4914176;        // NBLK*NBUCK int
static constexpr size_t OFF_OFFS  = 5714944;        // NBLK*NBUCK int
static constexpr size_t OFF_COL   = 6515712;        // E int
static constexpr size_t OFF_SRCB  = 19315712;       // E uchar
static constexpr size_t OFF_PAIRS = 22515712;       // E uint (s | dloc<<20)
static constexpr size_t OFF_H     = 35315712;       // N*128 bf16
static constexpr size_t OFF_T     = 60915712;       // N*128 bf16

__device__ inline float ldf(const float* p, int i) { return p[i]; }
__device__ inline float ldf(const __hip_bfloat16* p, int i) { return __bfloat162float(p[i]); }
__device__ inline float bflo(unsigned v) { return __uint_as_float(v << 16); }
__device__ inline float bfhi(unsigned v) { return __uint_as_float(v & 0xffff0000u); }
__device__ inline unsigned short bfbits(float x) {
    __hip_bfloat16 h = __float2bfloat16(x);
    return *reinterpret_cast<unsigned short*>(&h);
}

// ---- pass 1: per-block privatized bucket histograms (LDS atomics only) ----
__global__ __launch_bounds__(256) void k_count(const int* __restrict__ src,
                                               const int* __restrict__ dst,
                                               int* __restrict__ cnt_s,
                                               int* __restrict__ cnt_d) {
    __shared__ int hs[NBUCK], hd[NBUCK];
    int tid = threadIdx.x, blk = blockIdx.x;
    for (int b = tid; b < NBUCK; b += 256) { hs[b] = 0; hd[b] = 0; }
    __syncthreads();
    int e0 = blk * CHUNK, e1 = min(E, e0 + CHUNK);
    for (int e = e0 + tid; e < e1; e += 256) {
        atomicAdd(&hs[src[e] >> 7], 1);
        atomicAdd(&hd[dst[e] >> 7], 1);
    }
    __syncthreads();
    for (int b = tid; b < NBUCK; b += 256) {
        cnt_s[blk * NBUCK + b] = hs[b];
        cnt_d[blk * NBUCK + b] = hd[b];
    }
}

// ---- pass 2a: per-bucket scan over the 256 counting blocks ----
__global__ __launch_bounds__(256) void k_scanA(const int* __restrict__ cnt,
                                               int* __restrict__ off,
                                               int* __restrict__ tot) {
    __shared__ int sd[256];
    int b = blockIdx.x, tid = threadIdx.x;
    int v = cnt[tid * NBUCK + b];
    sd[tid] = v;
    __syncthreads();
    for (int o = 1; o < 256; o <<= 1) {
        int t = (tid >= o) ? sd[tid - o] : 0;
        __syncthreads();
        sd[tid] += t;
        __syncthreads();
    }
    off[tid * NBUCK + b] = sd[tid] - v;
    if (tid == 255) tot[b] = sd[255];
}

// ---- pass 2b: scan bucket totals -> bases ----
__global__ __launch_bounds__(1024) void k_scanB(const int* __restrict__ tot_d,
                                                const int* __restrict__ tot_s,
                                                int* __restrict__ dbase,
                                                int* __restrict__ sbase) {
    __shared__ int sd[1024], ss[1024];
    int tid = threadIdx.x;
    int vd = (tid < NBUCK) ? tot_d[tid] : 0;
    int vs = (tid < NBUCK) ? tot_s[tid] : 0;
    sd[tid] = vd; ss[tid] = vs;
    __syncthreads();
    for (int o = 1; o < 1024; o <<= 1) {
        int td = (tid >= o) ? sd[tid - o] : 0;
        int ts = (tid >= o) ? ss[tid - o] : 0;
        __syncthreads();
        sd[tid] += td; ss[tid] += ts;
        __syncthreads();
    }
    if (tid < NBUCK) { dbase[tid] = sd[tid] - vd; sbase[tid] = ss[tid] - vs; }
    if (tid == 0) { dbase[NBUCK] = E; sbase[NBUCK] = E; }
}

// ---- pass 3: deterministic-offset scatter (LDS cursors, zero global atomics) ----
__global__ __launch_bounds__(256) void k_scatter(const int* __restrict__ src,
                                                 const int* __restrict__ dst,
                                                 const int* __restrict__ dbase,
                                                 const int* __restrict__ sbase,
                                                 const int* __restrict__ offd,
                                                 const int* __restrict__ offs,
                                                 unsigned* __restrict__ pairs,
                                                 unsigned char* __restrict__ srcb) {
    __shared__ int cd[NBUCK], cs[NBUCK];
    int tid = threadIdx.x, blk = blockIdx.x;
    for (int b = tid; b < NBUCK; b += 256) {
        cd[b] = dbase[b] + offd[blk * NBUCK + b];
        cs[b] = sbase[b] + offs[blk * NBUCK + b];
    }
    __syncthreads();
    int e0 = blk * CHUNK, e1 = min(E, e0 + CHUNK);
    for (int e = e0 + tid; e < e1; e += 256) {
        int s = src[e], d = dst[e];
        int pd = atomicAdd(&cd[d >> 7], 1);
        pairs[pd] = (unsigned)s | ((unsigned)(d & 127) << 20);
        int ps = atomicAdd(&cs[s >> 7], 1);
        srcb[ps] = (unsigned char)(s & 127);
    }
}

// ---- pass 4: per-bucket degrees/norms/rp/col (LDS only) ----
__global__ __launch_bounds__(256) void k_build(const unsigned* __restrict__ pairs,
                                               const unsigned char* __restrict__ srcb,
                                               const int* __restrict__ dbase,
                                               const int* __restrict__ sbase,
                                               int* __restrict__ rp,
                                               float* __restrict__ norm_d,
                                               float* __restrict__ norm_s,
                                               int* __restrict__ col) {
    __shared__ int cnt[128], scn[128], lcur[128];
    int b = blockIdx.x, tid = threadIdx.x, node0 = b << 7;
    int nmax = min(128, N - node0);
    // src side: out-degree -> norm_s
    if (tid < 128) cnt[tid] = 0;
    __syncthreads();
    int sb = sbase[b], se = sbase[b + 1];
    for (int e = sb + tid; e < se; e += 256) atomicAdd(&cnt[srcb[e]], 1);
    __syncthreads();
    if (tid < nmax) norm_s[node0 + tid] = rsqrtf(fmaxf((float)cnt[tid], 1.0f));
    __syncthreads();
    // dst side: in-degree -> norm_d, rp, col
    if (tid < 128) cnt[tid] = 0;
    __syncthreads();
    int beg = dbase[b], end = dbase[b + 1];
    for (int e = beg + tid; e < end; e += 256) atomicAdd(&cnt[pairs[e] >> 20], 1);
    __syncthreads();
    if (tid < 128) scn[tid] = cnt[tid];
    __syncthreads();
    for (int o = 1; o < 128; o <<= 1) {
        int t = (tid < 128 && tid >= o) ? scn[tid - o] : 0;
        __syncthreads();
        if (tid < 128) scn[tid] += t;
        __syncthreads();
    }
    if (tid < nmax) {
        int excl = beg + scn[tid] - cnt[tid];
        rp[node0 + tid] = excl;
        lcur[tid] = excl;
        norm_d[node0 + tid] = rsqrtf(fmaxf((float)cnt[tid], 1.0f));
    }
    if (b == 0 && tid == 0) rp[N] = E;
    __syncthreads();
    for (int e = beg + tid; e < end; e += 256) {
        unsigned p = pairs[e];
        int pos = atomicAdd(&lcur[p >> 20], 1);
        col[pos] = (int)(p & 0xFFFFFu);
    }
}

// ---------------- GEMM: t = ((in * a + c) * norm_s) @ W, out bf16 ----------------
template <typename TIn, int FOUT, bool AFFINE>
__global__ __launch_bounds__(256) void k_gemm(const TIn* __restrict__ in,
                                              const float* __restrict__ W,
                                              const float* __restrict__ rowscale,
                                              const float* __restrict__ ab, // a[0..127], c[128..255]
                                              __hip_bfloat16* __restrict__ out) {
    __shared__ float Ws[64 * FOUT];
    __shared__ float Xs[32][128];
    const int tid = threadIdx.x;
    const int r0 = blockIdx.x * 32;

    for (int i = tid; i < 32 * 128; i += 256) {
        int rr = i >> 7, k = i & 127;
        int row = r0 + rr;
        float v = 0.0f;
        if (row < N) {
            v = ldf(in, row * 128 + k);
            if (AFFINE) v = v * ab[k] + ab[128 + k];
            v *= rowscale[row];
        }
        Xs[rr][k] = v;
    }

    const int wave = tid >> 6, lane = tid & 63;
    constexpr int NC = FOUT / 64;
    float acc[8][NC];
#pragma unroll
    for (int rr = 0; rr < 8; ++rr)
#pragma unroll
        for (int cc = 0; cc < NC; ++cc) acc[rr][cc] = 0.0f;

    for (int kb = 0; kb < 128; kb += 64) {
        __syncthreads();
        for (int i = tid; i < 64 * FOUT; i += 256)
            Ws[i] = W[(size_t)(kb + i / FOUT) * FOUT + (i % FOUT)];
        __syncthreads();
#pragma unroll 4
        for (int k = 0; k < 64; ++k) {
            float w0 = Ws[k * FOUT + lane];
            float w1 = (NC == 2) ? Ws[k * FOUT + 64 + lane] : 0.0f;
#pragma unroll
            for (int rr = 0; rr < 8; ++rr) {
                float xv = Xs[wave * 8 + rr][kb + k];
                acc[rr][0] += xv * w0;
                if (NC == 2) acc[rr][1] += xv * w1;
            }
        }
    }

#pragma unroll
    for (int rr = 0; rr < 8; ++rr) {
        int row = r0 + wave * 8 + rr;
        if (row < N) {
            out[(size_t)row * FOUT + lane] = __float2bfloat16(acc[rr][0]);
            if (NC == 2) out[(size_t)row * FOUT + lane + 64] = __float2bfloat16(acc[rr][1]);
        }
    }
}

// ------- fused aggregation (128 feats) + norm_d + bias + relu + bf16 H + BN partials -------
__global__ __launch_bounds__(256) void k_agg128f(const unsigned* __restrict__ T2, // N x 64 uints
                                                 const int* __restrict__ rp,
                                                 const int* __restrict__ col,
                                                 const float* __restrict__ norm_d,
                                                 const float* __restrict__ bias,
                                                 unsigned* __restrict__ Hu,      // N x 64 uints
                                                 float* __restrict__ part) {
    int tid = threadIdx.x, wave = tid >> 6, lane = tid & 63;
    int w = blockIdx.x * 4 + wave;
    int n0 = w * NCHUNK, n1 = min(N, n0 + NCHUNK);
    float bb0 = bias[2 * lane], bb1 = bias[2 * lane + 1];
    float s0 = 0.f, q0 = 0.f, s1 = 0.f, q1 = 0.f;
    for (int n = n0; n < n1; ++n) {
        int beg = rp[n], end = rp[n + 1];
        float a0 = 0.0f, a1 = 0.0f;
        int e = beg;
        for (; e + 8 <= end; e += 8) {
            int c0 = col[e],     c1 = col[e + 1], c2 = col[e + 2], c3 = col[e + 3];
            int c4 = col[e + 4], c5 = col[e + 5], c6 = col[e + 6], c7 = col[e + 7];
            unsigned v0 = T2[c0 * 64 + lane];
            unsigned v1 = T2[c1 * 64 + lane];
            unsigned v2 = T2[c2 * 64 + lane];
            unsigned v3 = T2[c3 * 64 + lane];
            unsigned v4 = T2[c4 * 64 + lane];
            unsigned v5 = T2[c5 * 64 + lane];
            unsigned v6 = T2[c6 * 64 + lane];
            unsigned v7 = T2[c7 * 64 + lane];
            a0 += bflo(v0) + bflo(v1) + bflo(v2) + bflo(v3)
                + bflo(v4) + bflo(v5) + bflo(v6) + bflo(v7);
            a1 += bfhi(v0) + bfhi(v1) + bfhi(v2) + bfhi(v3)
                + bfhi(v4) + bfhi(v5) + bfhi(v6) + bfhi(v7);
        }
        for (; e < end; ++e) {
            unsigned v = T2[col[e] * 64 + lane];
            a0 += bflo(v); a1 += bfhi(v);
        }
        float nd = norm_d[n];
        float r0 = fmaxf(a0 * nd + bb0, 0.0f);
        float r1 = fmaxf(a1 * nd + bb1, 0.0f);
        Hu[n * 64 + lane] = ((unsigned)bfbits(r1) << 16) | bfbits(r0);
        s0 += r0; q0 += r0 * r0; s1 += r1; q1 += r1 * r1;
    }
    __shared__ float red[4][256];
    red[wave][lane] = s0;
    red[wave][64 + lane] = q0;
    red[wave][128 + lane] = s1;
    red[wave][192 + lane] = q1;
    __syncthreads();
    float t = red[0][tid] + red[1][tid] + red[2][tid] + red[3][tid];
    part[blockIdx.x * 256 + tid] = t;
}

// reduce BN partials -> folded affine (a|c)
__global__ __launch_bounds__(256) void k_bnfin(const float* __restrict__ part,
                                               const float* __restrict__ gamma,
                                               const float* __restrict__ beta,
                                               float* __restrict__ ab) {
    __shared__ float slot[256];
    int tid = threadIdx.x;
    float a = 0.f;
    for (int blk = 0; blk < AGG_BLOCKS; blk += 4) {
        a += part[(blk + 0) * 256 + tid] + part[(blk + 1) * 256 + tid]
           + part[(blk + 2) * 256 + tid] + part[(blk + 3) * 256 + tid];
    }
    slot[tid] = a;
    __syncthreads();
    if (tid < 128) {
        int l = tid >> 1;
        float sum, sq;
        if ((tid & 1) == 0) { sum = slot[l];       sq = slot[64 + l]; }
        else                { sum = slot[128 + l]; sq = slot[192 + l]; }
        float mu = sum * (1.0f / N);
        float var = sq * (1.0f / N) - mu * mu;
        float aa = gamma[tid] * rsqrtf(var + BN_EPS);
        ab[tid] = aa;
        ab[128 + tid] = beta[tid] - mu * aa;
    }
}

// ------- fused aggregation (64 feats) + norm_d + bias + log_softmax -------
__global__ __launch_bounds__(256) void k_agg64f(const __hip_bfloat16* __restrict__ T,
                                                const int* __restrict__ rp,
                                                const int* __restrict__ col,
                                                const float* __restrict__ norm_d,
                                                const float* __restrict__ b3,
                                                float* __restrict__ out) {
    int wave = threadIdx.x >> 6, lane = threadIdx.x & 63;
    int n = blockIdx.x * 4 + wave;
    if (n >= N) return;
    int beg = rp[n], end = rp[n + 1];
    float a0 = 0.0f;
    int e = beg;
    for (; e + 8 <= end; e += 8) {
        int c0 = col[e],     c1 = col[e + 1], c2 = col[e + 2], c3 = col[e + 3];
        int c4 = col[e + 4], c5 = col[e + 5], c6 = col[e + 6], c7 = col[e + 7];
        float v0 = __bfloat162float(T[c0 * 64 + lane]);
        float v1 = __bfloat162float(T[c1 * 64 + lane]);
        float v2 = __bfloat162float(T[c2 * 64 + lane]);
        float v3 = __bfloat162float(T[c3 * 64 + lane]);
        float v4 = __bfloat162float(T[c4 * 64 + lane]);
        float v5 = __bfloat162float(T[c5 * 64 + lane]);
        float v6 = __bfloat162float(T[c6 * 64 + lane]);
        float v7 = __bfloat162float(T[c7 * 64 + lane]);
        a0 += v0 + v1 + v2 + v3 + v4 + v5 + v6 + v7;
    }
    for (; e < end; ++e) a0 += __bfloat162float(T[col[e] * 64 + lane]);
    float z = a0 * norm_d[n] + b3[lane];
    float m = z;
    for (int off = 32; off; off >>= 1) m = fmaxf(m, __shfl_xor(m, off));
    float ex = __expf(z - m);
    float ssum = ex;
    for (int off = 32; off; off >>= 1) ssum += __shfl_xor(ssum, off);
    out[n * 64 + lane] = z - m - __logf(ssum);
}

extern "C" void kernel_launch(void* const* d_in, const int* in_sizes, int n_in,
                              void* d_out, int out_size, void* d_ws, size_t ws_size,
                              hipStream_t stream) {
    const float* x  = (const float*)d_in[0];
    const int* src  = (const int*)d_in[1];
    const int* dst  = (const int*)d_in[2];
    const float* W1 = (const float*)d_in[3];
    const float* b1 = (const float*)d_in[4];
    const float* W2 = (const float*)d_in[5];
    const float* b2 = (const float*)d_in[6];
    const float* W3 = (const float*)d_in[7];
    const float* b3 = (const float*)d_in[8];
    const float* g1 = (const float*)d_in[9];
    const float* be1= (const float*)d_in[10];
    const float* g2 = (const float*)d_in[11];
    const float* be2= (const float*)d_in[12];
    float* out = (float*)d_out;

    char* ws = (char*)d_ws;
    int* tot_d = (int*)(ws + OFF_TOT_D);
    int* tot_s = (int*)(ws + OFF_TOT_S);
    int* dbase = (int*)(ws + OFF_DBASE);
    int* sbase = (int*)(ws + OFF_SBASE);
    float* ab1 = (float*)(ws + OFF_AB1);
    float* ab2 = (float*)(ws + OFF_AB2);
    float* bnp = (float*)(ws + OFF_BNP);
    float* norm_s = (float*)(ws + OFF_NORM_S);
    float* norm_d = (float*)(ws + OFF_NORM_D);
    int* rp = (int*)(ws + OFF_RP);
    int* cnt_d = (int*)(ws + OFF_CNT_D);
    int* cnt_s = (int*)(ws + OFF_CNT_S);
    int* offd = (int*)(ws + OFF_OFFD);
    int* offs = (int*)(ws + OFF_OFFS);
    int* col = (int*)(ws + OFF_COL);
    unsigned char* srcb = (unsigned char*)(ws + OFF_SRCB);
    unsigned* pairs = (unsigned*)(ws + OFF_PAIRS);
    __hip_bfloat16* H = (__hip_bfloat16*)(ws + OFF_H);
    __hip_bfloat16* T = (__hip_bfloat16*)(ws + OFF_T);

    // CSR build — zero global atomics
    k_count<<<NBLK, 256, 0, stream>>>(src, dst, cnt_s, cnt_d);
    k_scanA<<<NBUCK, 256, 0, stream>>>(cnt_d, offd, tot_d);
    k_scanA<<<NBUCK, 256, 0, stream>>>(cnt_s, offs, tot_s);
    k_scanB<<<1, 1024, 0, stream>>>(tot_d, tot_s, dbase, sbase);
    k_scatter<<<NBLK, 256, 0, stream>>>(src, dst, dbase, sbase, offd, offs, pairs, srcb);
    k_build<<<NBUCK, 256, 0, stream>>>(pairs, srcb, dbase, sbase, rp, norm_d, norm_s, col);

    const int gemm_grid = (N + 31) / 32;
    const int node_grid = (N + 3) / 4;

    // Layer 1
    k_gemm<float, 128, false><<<gemm_grid, 256, 0, stream>>>(x, W1, norm_s, nullptr, T);
    k_agg128f<<<AGG_BLOCKS, 256, 0, stream>>>((const unsigned*)T, rp, col, norm_d, b1, (unsigned*)H, bnp);
    k_bnfin<<<1, 256, 0, stream>>>(bnp, g1, be1, ab1);

    // Layer 2
    k_gemm<__hip_bfloat16, 128, true><<<gemm_grid, 256, 0, stream>>>(H, W2, norm_s, ab1, T);
    k_agg128f<<<AGG_BLOCKS, 256, 0, stream>>>((const unsigned*)T, rp, col, norm_d, b2, (unsigned*)H, bnp);
    k_bnfin<<<1, 256, 0, stream>>>(bnp, g2, be2, ab2);

    // Layer 3 (64 outputs) + log_softmax
    k_gemm<__hip_bfloat16, 64, true><<<gemm_grid, 256, 0, stream>>>(H, W3, norm_s, ab2, T);
    k_agg64f<<<node_grid, 256, 0, stream>>>(T, rp, col, norm_d, b3, out);
}

// Round 6
// 656.049 us; speedup vs baseline: 2.3694x; 1.3741x over previous
//
#include <hip/hip_runtime.h>
#include <hip/hip_bf16.h>
#include <cstdint>

// Problem constants (fixed by the reference).
static constexpr int N = 100000;
static constexpr int E = 3200000;
static constexpr float BN_EPS = 1e-5f;
static constexpr int NBUCK = (N + 127) >> 7;   // 782 buckets of 128 nodes
static constexpr int NBLK = 256;               // edge-counting blocks
static constexpr int CHUNK = E / NBLK;         // 12500 edges per block (exact)
static constexpr int AGG_BLOCKS = 2048;        // 8192 waves = 100% occupancy cap
static constexpr int NWAVE = AGG_BLOCKS * 4;   // edge-balanced wave partitions

// ---------------- workspace layout (no zero-init required anywhere) ----------------
static constexpr size_t OFF_TOT_D = 0;              // NBUCK int
static constexpr size_t OFF_TOT_S = 3328;           // NBUCK int
static constexpr size_t OFF_DBASE = 6656;           // NBUCK+1 int
static constexpr size_t OFF_SBASE = 9984;           // NBUCK+1 int
static constexpr size_t OFF_AB1   = 13312;          // 256 f32 (a|c)
static constexpr size_t OFF_AB2   = 14336;          // 256 f32
static constexpr size_t OFF_CVEC  = 15360;          // 128 f32
static constexpr size_t OFF_WT    = 16384;          // 128*128 bf16 (transposed, affine-folded W)
static constexpr size_t OFF_WSRT  = 49152;          // NWAVE+1 int (balanced wave starts)
static constexpr size_t OFF_BNP2  = 82944;          // 64*256 f32
static constexpr size_t OFF_BNP   = 148480;         // AGG_BLOCKS*256 f32 = 2 MB
static constexpr size_t OFF_NORM_S= 2245632;        // N f32
static constexpr size_t OFF_NORM_D= 2645632;        // N f32
static constexpr size_t OFF_RP    = 3045632;        // N+1 int
static constexpr size_t OFF_CNT_D = 3445760;        // NBLK*NBUCK int
static constexpr size_t OFF_CNT_S = 4246528;        // NBLK*NBUCK int
static constexpr size_t OFF_OFFD  = 5047296;        // NBLK*NBUCK int
static constexpr size_t OFF_OFFS  = 5848064;        // NBLK*NBUCK int
static constexpr size_t OFF_COL   = 6648832;        // E int
static constexpr size_t OFF_SRCB  = 19448832;       // E uchar
static constexpr size_t OFF_PAIRS = 22648832;       // E uint (s | dloc<<20)
static constexpr size_t OFF_H     = 35448832;       // N*128 bf16
static constexpr size_t OFF_T     = 61048832;       // N*128 bf16

using short8  = __attribute__((ext_vector_type(8))) short;
using float4v = __attribute__((ext_vector_type(4))) float;

__device__ inline float bflo(unsigned v) { return __uint_as_float(v << 16); }
__device__ inline float bfhi(unsigned v) { return __uint_as_float(v & 0xffff0000u); }
__device__ inline unsigned short bfbits(float x) {
    __hip_bfloat16 h = __float2bfloat16(x);
    return *reinterpret_cast<unsigned short*>(&h);
}

// ---- pass 1: per-block privatized bucket histograms (LDS atomics only) ----
__global__ __launch_bounds__(256) void k_count(const int* __restrict__ src,
                                               const int* __restrict__ dst,
                                               int* __restrict__ cnt_s,
                                               int* __restrict__ cnt_d) {
    __shared__ int hs[NBUCK], hd[NBUCK];
    int tid = threadIdx.x, blk = blockIdx.x;
    for (int b = tid; b < NBUCK; b += 256) { hs[b] = 0; hd[b] = 0; }
    __syncthreads();
    int e0 = blk * CHUNK, e1 = min(E, e0 + CHUNK);
    for (int e = e0 + tid; e < e1; e += 256) {
        atomicAdd(&hs[src[e] >> 7], 1);
        atomicAdd(&hd[dst[e] >> 7], 1);
    }
    __syncthreads();
    for (int b = tid; b < NBUCK; b += 256) {
        cnt_s[blk * NBUCK + b] = hs[b];
        cnt_d[blk * NBUCK + b] = hd[b];
    }
}

// ---- pass 2a: per-bucket scan over the 256 counting blocks ----
__global__ __launch_bounds__(256) void k_scanA(const int* __restrict__ cnt,
                                               int* __restrict__ off,
                                               int* __restrict__ tot) {
    __shared__ int sd[256];
    int b = blockIdx.x, tid = threadIdx.x;
    int v = cnt[tid * NBUCK + b];
    sd[tid] = v;
    __syncthreads();
    for (int o = 1; o < 256; o <<= 1) {
        int t = (tid >= o) ? sd[tid - o] : 0;
        __syncthreads();
        sd[tid] += t;
        __syncthreads();
    }
    off[tid * NBUCK + b] = sd[tid] - v;
    if (tid == 255) tot[b] = sd[255];
}

// ---- pass 2b: scan bucket totals -> bases ----
__global__ __launch_bounds__(1024) void k_scanB(const int* __restrict__ tot_d,
                                                const int* __restrict__ tot_s,
                                                int* __restrict__ dbase,
                                                int* __restrict__ sbase) {
    __shared__ int sd[1024], ss[1024];
    int tid = threadIdx.x;
    int vd = (tid < NBUCK) ? tot_d[tid] : 0;
    int vs = (tid < NBUCK) ? tot_s[tid] : 0;
    sd[tid] = vd; ss[tid] = vs;
    __syncthreads();
    for (int o = 1; o < 1024; o <<= 1) {
        int td = (tid >= o) ? sd[tid - o] : 0;
        int ts = (tid >= o) ? ss[tid - o] : 0;
        __syncthreads();
        sd[tid] += td; ss[tid] += ts;
        __syncthreads();
    }
    if (tid < NBUCK) { dbase[tid] = sd[tid] - vd; sbase[tid] = ss[tid] - vs; }
    if (tid == 0) { dbase[NBUCK] = E; sbase[NBUCK] = E; }
}

// ---- pass 3: deterministic-offset scatter (LDS cursors, zero global atomics) ----
__global__ __launch_bounds__(256) void k_scatter(const int* __restrict__ src,
                                                 const int* __restrict__ dst,
                                                 const int* __restrict__ dbase,
                                                 const int* __restrict__ sbase,
                                                 const int* __restrict__ offd,
                                                 const int* __restrict__ offs,
                                                 unsigned* __restrict__ pairs,
                                                 unsigned char* __restrict__ srcb) {
    __shared__ int cd[NBUCK], cs[NBUCK];
    int tid = threadIdx.x, blk = blockIdx.x;
    for (int b = tid; b < NBUCK; b += 256) {
        cd[b] = dbase[b] + offd[blk * NBUCK + b];
        cs[b] = sbase[b] + offs[blk * NBUCK + b];
    }
    __syncthreads();
    int e0 = blk * CHUNK, e1 = min(E, e0 + CHUNK);
    for (int e = e0 + tid; e < e1; e += 256) {
        int s = src[e], d = dst[e];
        int pd = atomicAdd(&cd[d >> 7], 1);
        pairs[pd] = (unsigned)s | ((unsigned)(d & 127) << 20);
        int ps = atomicAdd(&cs[s >> 7], 1);
        srcb[ps] = (unsigned char)(s & 127);
    }
}

// ---- pass 4: per-bucket degrees/norms/rp/col (LDS only) ----
__global__ __launch_bounds__(256) void k_build(const unsigned* __restrict__ pairs,
                                               const unsigned char* __restrict__ srcb,
                                               const int* __restrict__ dbase,
                                               const int* __restrict__ sbase,
                                               int* __restrict__ rp,
                                               float* __restrict__ norm_d,
                                               float* __restrict__ norm_s,
                                               int* __restrict__ col) {
    __shared__ int cnt[128], scn[128], lcur[128];
    int b = blockIdx.x, tid = threadIdx.x, node0 = b << 7;
    int nmax = min(128, N - node0);
    if (tid < 128) cnt[tid] = 0;
    __syncthreads();
    int sb = sbase[b], se = sbase[b + 1];
    for (int e = sb + tid; e < se; e += 256) atomicAdd(&cnt[srcb[e]], 1);
    __syncthreads();
    if (tid < nmax) norm_s[node0 + tid] = rsqrtf(fmaxf((float)cnt[tid], 1.0f));
    __syncthreads();
    if (tid < 128) cnt[tid] = 0;
    __syncthreads();
    int beg = dbase[b], end = dbase[b + 1];
    for (int e = beg + tid; e < end; e += 256) atomicAdd(&cnt[pairs[e] >> 20], 1);
    __syncthreads();
    if (tid < 128) scn[tid] = cnt[tid];
    __syncthreads();
    for (int o = 1; o < 128; o <<= 1) {
        int t = (tid < 128 && tid >= o) ? scn[tid - o] : 0;
        __syncthreads();
        if (tid < 128) scn[tid] += t;
        __syncthreads();
    }
    if (tid < nmax) {
        int excl = beg + scn[tid] - cnt[tid];
        rp[node0 + tid] = excl;
        lcur[tid] = excl;
        norm_d[node0 + tid] = rsqrtf(fmaxf((float)cnt[tid], 1.0f));
    }
    if (b == 0 && tid == 0) rp[N] = E;
    __syncthreads();
    for (int e = beg + tid; e < end; e += 256) {
        unsigned p = pairs[e];
        int pos = atomicAdd(&lcur[p >> 20], 1);
        col[pos] = (int)(p & 0xFFFFFu);
    }
}

// ---- edge-balanced wave partition: wsrt[w] = first node of wave w ----
__global__ __launch_bounds__(256) void k_wpart(const int* __restrict__ rp,
                                               int* __restrict__ wsrt) {
    int w = blockIdx.x * 256 + threadIdx.x;
    if (w > NWAVE) return;
    if (w == 0) { wsrt[0] = 0; return; }
    if (w == NWAVE) { wsrt[NWAVE] = N; return; }
    int t = (int)((long long)w * E / NWAVE);
    int lo = 0, hi = N;
    while (lo < hi) { int mid = (lo + hi) >> 1; if (rp[mid] >= t) hi = mid; else lo = mid + 1; }
    wsrt[w] = lo;
}

// ---- W prep: Wt[n][k] = bf16(a[k]*W[k][n]) (transposed), cvec[n] = sum_k c[k]*W[k][n] ----
template <bool AFFINE>
__global__ __launch_bounds__(64) void k_wprep(const float* __restrict__ W,
                                              const float* __restrict__ ab,
                                              int fout,
                                              unsigned short* __restrict__ Wt,
                                              float* __restrict__ cvec) {
    int n = blockIdx.x, k = threadIdx.x;
    float w0 = W[k * fout + n], w1 = W[(k + 64) * fout + n];
    float a0 = AFFINE ? ab[k] : 1.0f;
    float a1 = AFFINE ? ab[k + 64] : 1.0f;
    Wt[n * 128 + k] = bfbits(a0 * w0);
    Wt[n * 128 + k + 64] = bfbits(a1 * w1);
    float cv = AFFINE ? (ab[128 + k] * w0 + ab[192 + k] * w1) : 0.0f;
    for (int o = 32; o; o >>= 1) cv += __shfl_xor(cv, o);
    if (k == 0) cvec[n] = cv;
}

// ---- MFMA GEMM: T = ns .* (Xbf16 @ Wt^T) + ns .* cvec ; 128 rows x FOUT per block ----
template <typename TIn, int FOUT>
__global__ __launch_bounds__(256) void k_gemm(const TIn* __restrict__ in,
                                              const unsigned short* __restrict__ Wt,
                                              const float* __restrict__ cvec,
                                              const float* __restrict__ ns,
                                              unsigned short* __restrict__ out) {
    constexpr int PK = 72;  // 64 + 8 pad: 2-way LDS conflict (free) on frag reads
    __shared__ __align__(16) unsigned short Xs[128 * PK];
    __shared__ __align__(16) unsigned short Wsh[FOUT * PK];
    const int tid = threadIdx.x;
    const int r0 = blockIdx.x * 128;
    const int wave = tid >> 6, lane = tid & 63;
    const int l16 = lane & 15, quad = lane >> 4;
    constexpr int MT = (FOUT == 128) ? 4 : 2;
    constexpr int NT = 4;
    const int wm = (FOUT == 128) ? (wave >> 1) : wave;
    const int wn = (FOUT == 128) ? (wave & 1) : 0;
    const int mbase = wm * (MT * 16);
    const int nbase = wn * 64;

    float4v acc[MT][NT];
#pragma unroll
    for (int mt = 0; mt < MT; ++mt)
#pragma unroll
        for (int nt = 0; nt < NT; ++nt) acc[mt][nt] = (float4v){0.f, 0.f, 0.f, 0.f};

    for (int kb = 0; kb < 128; kb += 64) {
        __syncthreads();
        // stage X half-K (bf16), rows >= N zeroed
        for (int i = tid; i < 128 * 8; i += 256) {
            int row = i >> 3, j = i & 7;
            int grow = r0 + row;
            if constexpr (sizeof(TIn) == 4) {
                short8 p = {0, 0, 0, 0, 0, 0, 0, 0};
                if (grow < N) {
                    const float* g = (const float*)in + (size_t)grow * 128 + kb + j * 8;
                    float4 f0 = *(const float4*)g;
                    float4 f1 = *(const float4*)(g + 4);
                    p[0] = (short)bfbits(f0.x); p[1] = (short)bfbits(f0.y);
                    p[2] = (short)bfbits(f0.z); p[3] = (short)bfbits(f0.w);
                    p[4] = (short)bfbits(f1.x); p[5] = (short)bfbits(f1.y);
                    p[6] = (short)bfbits(f1.z); p[7] = (short)bfbits(f1.w);
                }
                *(short8*)&Xs[row * PK + j * 8] = p;
            } else {
                uint4 v = make_uint4(0, 0, 0, 0);
                if (grow < N)
                    v = *(const uint4*)((const unsigned short*)in + (size_t)grow * 128 + kb + j * 8);
                *(uint4*)&Xs[row * PK + j * 8] = v;
            }
        }
        // stage Wt half-K (already transposed in global)
        for (int i = tid; i < FOUT * 8; i += 256) {
            int n = i >> 3, j = i & 7;
            uint4 v = *(const uint4*)&Wt[n * 128 + kb + j * 8];
            *(uint4*)&Wsh[n * PK + j * 8] = v;
        }
        __syncthreads();
#pragma unroll
        for (int ks = 0; ks < 64; ks += 32) {
            short8 af[MT], bfr[NT];
#pragma unroll
            for (int mt = 0; mt < MT; ++mt)
                af[mt] = *(const short8*)&Xs[(mbase + mt * 16 + l16) * PK + ks + quad * 8];
#pragma unroll
            for (int nt = 0; nt < NT; ++nt)
                bfr[nt] = *(const short8*)&Wsh[(nbase + nt * 16 + l16) * PK + ks + quad * 8];
#pragma unroll
            for (int mt = 0; mt < MT; ++mt)
#pragma unroll
                for (int nt = 0; nt < NT; ++nt)
                    acc[mt][nt] = __builtin_amdgcn_mfma_f32_16x16x32_bf16(
                        af[mt], bfr[nt], acc[mt][nt], 0, 0, 0);
        }
    }
    float cv[NT];
#pragma unroll
    for (int nt = 0; nt < NT; ++nt) cv[nt] = cvec[nbase + nt * 16 + l16];
#pragma unroll
    for (int mt = 0; mt < MT; ++mt) {
#pragma unroll
        for (int r = 0; r < 4; ++r) {
            int row = r0 + mbase + mt * 16 + quad * 4 + r;
            if (row < N) {
                float s = ns[row];
#pragma unroll
                for (int nt = 0; nt < NT; ++nt)
                    out[(size_t)row * FOUT + nbase + nt * 16 + l16] =
                        bfbits((acc[mt][nt][r] + cv[nt]) * s);
            }
        }
    }
}

// ------- fused aggregation (128 feats) + norm_d + bias + relu + bf16 H + BN partials -------
__global__ __launch_bounds__(256) void k_agg128f(const unsigned* __restrict__ T2, // N x 64 uints
                                                 const int* __restrict__ wsrt,
                                                 const int* __restrict__ rp,
                                                 const int* __restrict__ col,
                                                 const float* __restrict__ norm_d,
                                                 const float* __restrict__ bias,
                                                 unsigned* __restrict__ Hu,      // N x 64 uints
                                                 float* __restrict__ part) {
    int tid = threadIdx.x, wave = tid >> 6, lane = tid & 63;
    int w = blockIdx.x * 4 + wave;
    int n0 = wsrt[w], n1 = wsrt[w + 1];
    float bb0 = bias[2 * lane], bb1 = bias[2 * lane + 1];
    float s0 = 0.f, q0 = 0.f, s1 = 0.f, q1 = 0.f;
    for (int n = n0; n < n1; ++n) {
        int beg = rp[n], end = rp[n + 1];
        float a0 = 0.0f, a1 = 0.0f;
        int e = beg;
        for (; e + 8 <= end; e += 8) {
            int c0 = col[e],     c1 = col[e + 1], c2 = col[e + 2], c3 = col[e + 3];
            int c4 = col[e + 4], c5 = col[e + 5], c6 = col[e + 6], c7 = col[e + 7];
            unsigned v0 = T2[c0 * 64 + lane];
            unsigned v1 = T2[c1 * 64 + lane];
            unsigned v2 = T2[c2 * 64 + lane];
            unsigned v3 = T2[c3 * 64 + lane];
            unsigned v4 = T2[c4 * 64 + lane];
            unsigned v5 = T2[c5 * 64 + lane];
            unsigned v6 = T2[c6 * 64 + lane];
            unsigned v7 = T2[c7 * 64 + lane];
            a0 += bflo(v0) + bflo(v1) + bflo(v2) + bflo(v3)
                + bflo(v4) + bflo(v5) + bflo(v6) + bflo(v7);
            a1 += bfhi(v0) + bfhi(v1) + bfhi(v2) + bfhi(v3)
                + bfhi(v4) + bfhi(v5) + bfhi(v6) + bfhi(v7);
        }
        for (; e < end; ++e) {
            unsigned v = T2[col[e] * 64 + lane];
            a0 += bflo(v); a1 += bfhi(v);
        }
        float nd = norm_d[n];
        float r0 = fmaxf(a0 * nd + bb0, 0.0f);
        float r1 = fmaxf(a1 * nd + bb1, 0.0f);
        Hu[n * 64 + lane] = ((unsigned)bfbits(r1) << 16) | bfbits(r0);
        s0 += r0; q0 += r0 * r0; s1 += r1; q1 += r1 * r1;
    }
    __shared__ float red[4][256];
    red[wave][lane] = s0;
    red[wave][64 + lane] = q0;
    red[wave][128 + lane] = s1;
    red[wave][192 + lane] = q1;
    __syncthreads();
    float t = red[0][tid] + red[1][tid] + red[2][tid] + red[3][tid];
    part[blockIdx.x * 256 + tid] = t;
}

// hierarchical BN partial reduce: 2048 rows -> 64 rows
__global__ __launch_bounds__(256) void k_bnred(const float* __restrict__ part,
                                               float* __restrict__ part2) {
    int b = blockIdx.x, tid = threadIdx.x;
    float s = 0.f;
    for (int i = 0; i < AGG_BLOCKS / 64; ++i)
        s += part[(b * (AGG_BLOCKS / 64) + i) * 256 + tid];
    part2[b * 256 + tid] = s;
}

// reduce 64 partial rows -> folded affine (a|c)
__global__ __launch_bounds__(256) void k_bnfin(const float* __restrict__ part2,
                                               const float* __restrict__ gamma,
                                               const float* __restrict__ beta,
                                               float* __restrict__ ab) {
    __shared__ float slot[256];
    int tid = threadIdx.x;
    float a = 0.f;
    for (int b = 0; b < 64; ++b) a += part2[b * 256 + tid];
    slot[tid] = a;
    __syncthreads();
    if (tid < 128) {
        int l = tid >> 1;
        float sum, sq;
        if ((tid & 1) == 0) { sum = slot[l];       sq = slot[64 + l]; }
        else                { sum = slot[128 + l]; sq = slot[192 + l]; }
        float mu = sum * (1.0f / N);
        float var = sq * (1.0f / N) - mu * mu;
        float aa = gamma[tid] * rsqrtf(var + BN_EPS);
        ab[tid] = aa;
        ab[128 + tid] = beta[tid] - mu * aa;
    }
}

// ------- fused aggregation (64 feats) + norm_d + bias + log_softmax -------
__global__ __launch_bounds__(256) void k_agg64f(const __hip_bfloat16* __restrict__ T,
                                                const int* __restrict__ wsrt,
                                                const int* __restrict__ rp,
                                                const int* __restrict__ col,
                                                const float* __restrict__ norm_d,
                                                const float* __restrict__ b3,
                                                float* __restrict__ out) {
    int wave = threadIdx.x >> 6, lane = threadIdx.x & 63;
    int w = blockIdx.x * 4 + wave;
    int n0 = wsrt[w], n1 = wsrt[w + 1];
    float bb = b3[lane];
    for (int n = n0; n < n1; ++n) {
        int beg = rp[n], end = rp[n + 1];
        float a0 = 0.0f;
        int e = beg;
        for (; e + 8 <= end; e += 8) {
            int c0 = col[e],     c1 = col[e + 1], c2 = col[e + 2], c3 = col[e + 3];
            int c4 = col[e + 4], c5 = col[e + 5], c6 = col[e + 6], c7 = col[e + 7];
            float v0 = __bfloat162float(T[c0 * 64 + lane]);
            float v1 = __bfloat162float(T[c1 * 64 + lane]);
            float v2 = __bfloat162float(T[c2 * 64 + lane]);
            float v3 = __bfloat162float(T[c3 * 64 + lane]);
            float v4 = __bfloat162float(T[c4 * 64 + lane]);
            float v5 = __bfloat162float(T[c5 * 64 + lane]);
            float v6 = __bfloat162float(T[c6 * 64 + lane]);
            float v7 = __bfloat162float(T[c7 * 64 + lane]);
            a0 += v0 + v1 + v2 + v3 + v4 + v5 + v6 + v7;
        }
        for (; e < end; ++e) a0 += __bfloat162float(T[col[e] * 64 + lane]);
        float z = a0 * norm_d[n] + bb;
        float m = z;
        for (int off = 32; off; off >>= 1) m = fmaxf(m, __shfl_xor(m, off));
        float ex = __expf(z - m);
        float ssum = ex;
        for (int off = 32; off; off >>= 1) ssum += __shfl_xor(ssum, off);
        out[n * 64 + lane] = z - m - __logf(ssum);
    }
}

extern "C" void kernel_launch(void* const* d_in, const int* in_sizes, int n_in,
                              void* d_out, int out_size, void* d_ws, size_t ws_size,
                              hipStream_t stream) {
    const float* x  = (const float*)d_in[0];
    const int* src  = (const int*)d_in[1];
    const int* dst  = (const int*)d_in[2];
    const float* W1 = (const float*)d_in[3];
    const float* b1 = (const float*)d_in[4];
    const float* W2 = (const float*)d_in[5];
    const float* b2 = (const float*)d_in[6];
    const float* W3 = (const float*)d_in[7];
    const float* b3 = (const float*)d_in[8];
    const float* g1 = (const float*)d_in[9];
    const float* be1= (const float*)d_in[10];
    const float* g2 = (const float*)d_in[11];
    const float* be2= (const float*)d_in[12];
    float* out = (float*)d_out;

    char* ws = (char*)d_ws;
    int* tot_d = (int*)(ws + OFF_TOT_D);
    int* tot_s = (int*)(ws + OFF_TOT_S);
    int* dbase = (int*)(ws + OFF_DBASE);
    int* sbase = (int*)(ws + OFF_SBASE);
    float* ab1 = (float*)(ws + OFF_AB1);
    float* ab2 = (float*)(ws + OFF_AB2);
    float* cvec = (float*)(ws + OFF_CVEC);
    unsigned short* Wt = (unsigned short*)(ws + OFF_WT);
    int* wsrt = (int*)(ws + OFF_WSRT);
    float* bnp2 = (float*)(ws + OFF_BNP2);
    float* bnp = (float*)(ws + OFF_BNP);
    float* norm_s = (float*)(ws + OFF_NORM_S);
    float* norm_d = (float*)(ws + OFF_NORM_D);
    int* rp = (int*)(ws + OFF_RP);
    int* cnt_d = (int*)(ws + OFF_CNT_D);
    int* cnt_s = (int*)(ws + OFF_CNT_S);
    int* offd = (int*)(ws + OFF_OFFD);
    int* offs = (int*)(ws + OFF_OFFS);
    int* col = (int*)(ws + OFF_COL);
    unsigned char* srcb = (unsigned char*)(ws + OFF_SRCB);
    unsigned* pairs = (unsigned*)(ws + OFF_PAIRS);
    unsigned short* H = (unsigned short*)(ws + OFF_H);
    unsigned short* T = (unsigned short*)(ws + OFF_T);

    // CSR build — zero global atomics
    k_count<<<NBLK, 256, 0, stream>>>(src, dst, cnt_s, cnt_d);
    k_scanA<<<NBUCK, 256, 0, stream>>>(cnt_d, offd, tot_d);
    k_scanA<<<NBUCK, 256, 0, stream>>>(cnt_s, offs, tot_s);
    k_scanB<<<1, 1024, 0, stream>>>(tot_d, tot_s, dbase, sbase);
    k_scatter<<<NBLK, 256, 0, stream>>>(src, dst, dbase, sbase, offd, offs, pairs, srcb);
    k_build<<<NBUCK, 256, 0, stream>>>(pairs, srcb, dbase, sbase, rp, norm_d, norm_s, col);
    k_wpart<<<(NWAVE + 256) / 256, 256, 0, stream>>>(rp, wsrt);

    const int gemm_grid = (N + 127) / 128;

    // Layer 1
    k_wprep<false><<<128, 64, 0, stream>>>(W1, nullptr, 128, Wt, cvec);
    k_gemm<float, 128><<<gemm_grid, 256, 0, stream>>>(x, Wt, cvec, norm_s, T);
    k_agg128f<<<AGG_BLOCKS, 256, 0, stream>>>((const unsigned*)T, wsrt, rp, col, norm_d, b1, (unsigned*)H, bnp);
    k_bnred<<<64, 256, 0, stream>>>(bnp, bnp2);
    k_bnfin<<<1, 256, 0, stream>>>(bnp2, g1, be1, ab1);

    // Layer 2
    k_wprep<true><<<128, 64, 0, stream>>>(W2, ab1, 128, Wt, cvec);
    k_gemm<__hip_bfloat16, 128><<<gemm_grid, 256, 0, stream>>>((const __hip_bfloat16*)H, Wt, cvec, norm_s, T);
    k_agg128f<<<AGG_BLOCKS, 256, 0, stream>>>((const unsigned*)T, wsrt, rp, col, norm_d, b2, (unsigned*)H, bnp);
    k_bnred<<<64, 256, 0, stream>>>(bnp, bnp2);
    k_bnfin<<<1, 256, 0, stream>>>(bnp2, g2, be2, ab2);

    // Layer 3 (64 outputs) + log_softmax
    k_wprep<true><<<64, 64, 0, stream>>>(W3, ab2, 64, Wt, cvec);
    k_gemm<__hip_bfloat16, 64><<<gemm_grid, 256, 0, stream>>>((const __hip_bfloat16*)H, Wt, cvec, norm_s, T);
    k_agg64f<<<AGG_BLOCKS, 256, 0, stream>>>((const __hip_bfloat16*)T, wsrt, rp, col, norm_d, b3, out);
}